// Round 1
// baseline (1755.696 us; speedup 1.0000x reference)
//
#include <hip/hip_runtime.h>
#include <hip/hip_bf16.h>
#include <math.h>

// Problem constants
constexpr int kB = 4;
constexpr int kT = 1024;
constexpr int kC = 1024;
constexpr int kH = 16;
constexpr int kD = 64;     // head dim
constexpr int kF = 4096;   // ffn hidden
constexpr int kBT = kB * kT;  // 4096 rows

// ---------------------------------------------------------------------------
// LayerNorm: one block per row (C=1024), 256 threads, float4 per thread.
// ---------------------------------------------------------------------------
__global__ __launch_bounds__(256) void ln_kernel(const float* __restrict__ x,
                                                 const float* __restrict__ g,
                                                 const float* __restrict__ bta,
                                                 float* __restrict__ out) {
    int row = blockIdx.x;
    int t = threadIdx.x;
    const float4* xr = (const float4*)(x + (size_t)row * kC);
    float4 xv = xr[t];
    float s  = xv.x + xv.y + xv.z + xv.w;
    float sq = xv.x * xv.x + xv.y * xv.y + xv.z * xv.z + xv.w * xv.w;
    #pragma unroll
    for (int off = 32; off; off >>= 1) {
        s  += __shfl_xor(s, off);
        sq += __shfl_xor(sq, off);
    }
    __shared__ float sb[8];
    int wid = t >> 6, lane = t & 63;
    if (lane == 0) { sb[wid] = s; sb[4 + wid] = sq; }
    __syncthreads();
    s  = sb[0] + sb[1] + sb[2] + sb[3];
    sq = sb[4] + sb[5] + sb[6] + sb[7];
    float mean = s * (1.0f / kC);
    float var  = sq * (1.0f / kC) - mean * mean;
    float rs = rsqrtf(var + 1e-5f);
    float4 gv = ((const float4*)g)[t];
    float4 bv = ((const float4*)bta)[t];
    float4 o;
    o.x = (xv.x - mean) * rs * gv.x + bv.x;
    o.y = (xv.y - mean) * rs * gv.y + bv.y;
    o.z = (xv.z - mean) * rs * gv.z + bv.z;
    o.w = (xv.w - mean) * rs * gv.w + bv.w;
    ((float4*)(out + (size_t)row * kC))[t] = o;
}

// ---------------------------------------------------------------------------
// QKV projection GEMM: h(4096x1024) x packed W(1024x3072) -> q/k/v in
// (B,H,T,D) layout. Tile 64x64x16, 256 threads, 4x4 per thread.
// grid = (48, 64)
// ---------------------------------------------------------------------------
__global__ __launch_bounds__(256) void qkv_kernel(const float* __restrict__ A,
                                                  const float* __restrict__ Wq,
                                                  const float* __restrict__ Wk,
                                                  const float* __restrict__ Wv,
                                                  float* __restrict__ qo,
                                                  float* __restrict__ ko,
                                                  float* __restrict__ vo) {
    __shared__ float As[16][64];
    __shared__ float Bs[16][68];
    int tid = threadIdx.x;
    int bm = blockIdx.y * 64;
    int bn = blockIdx.x * 64;          // 0..3071
    int which = bn >> 10;              // 0=q,1=k,2=v
    int head = (bn & 1023) >> 6;
    const float* W = (which == 0) ? Wq : (which == 1) ? Wk : Wv;
    const float* Wb = W + (size_t)head * kC * kD;   // (C, D) for this head
    int tx = tid & 15, ty = tid >> 4;
    float acc[4][4] = {};
    for (int k0 = 0; k0 < kC; k0 += 16) {
        {
            int r = tid >> 2, c4 = (tid & 3) * 4;
            float4 a = *(const float4*)(A + (size_t)(bm + r) * kC + k0 + c4);
            As[c4 + 0][r] = a.x; As[c4 + 1][r] = a.y;
            As[c4 + 2][r] = a.z; As[c4 + 3][r] = a.w;
        }
        {
            int r = tid >> 4, d4 = (tid & 15) * 4;
            float4 b = *(const float4*)(Wb + (size_t)(k0 + r) * kD + d4);
            *(float4*)&Bs[r][d4] = b;
        }
        __syncthreads();
        #pragma unroll
        for (int kk = 0; kk < 16; kk++) {
            float4 av = *(const float4*)&As[kk][ty * 4];
            float4 bv = *(const float4*)&Bs[kk][tx * 4];
            float aa[4] = {av.x, av.y, av.z, av.w};
            float bb[4] = {bv.x, bv.y, bv.z, bv.w};
            #pragma unroll
            for (int i = 0; i < 4; i++)
                #pragma unroll
                for (int j = 0; j < 4; j++)
                    acc[i][j] += aa[i] * bb[j];
        }
        __syncthreads();
    }
    float* outp = (which == 0) ? qo : (which == 1) ? ko : vo;
    #pragma unroll
    for (int i = 0; i < 4; i++) {
        int m = bm + ty * 4 + i;
        int b = m >> 10, t = m & 1023;
        float4 o = make_float4(acc[i][0], acc[i][1], acc[i][2], acc[i][3]);
        *(float4*)(outp + (((size_t)(b * kH + head) * kT + t) * kD) + tx * 4) = o;
    }
}

// ---------------------------------------------------------------------------
// Attention: flash-style, one block per (b, head, 64 t-rows). Full-range
// s in [0,T) with exact reference masking:
//   score = padded[s] ? -1e9 : (s <= t ? qk/32 : -inf)
// This reproduces the reference's where(padding, -1e9, where(causal, qk, -inf))
// including the "all visible keys padded -> attend uniformly to ALL padded
// keys (even future ones)" corner case.
// grid = (16, 64), 256 threads.
// ---------------------------------------------------------------------------
__global__ __launch_bounds__(256) void attn_kernel(const float* __restrict__ q,
                                                   const float* __restrict__ kg,
                                                   const float* __restrict__ vg,
                                                   const int* __restrict__ pad,
                                                   float* __restrict__ out) {
    __shared__ float Qs[64][68];   // [d][t]
    __shared__ float KPs[64][68];  // [d][s] for K, then [s][r] for P
    __shared__ float Vs[64][68];   // [s][d]
    __shared__ int padf[64];
    int bh = blockIdx.y;
    int b = bh >> 4, head = bh & 15;
    int t0 = blockIdx.x * 64;
    const float* qb = q  + (size_t)bh * kT * kD;
    const float* kb = kg + (size_t)bh * kT * kD;
    const float* vb = vg + (size_t)bh * kT * kD;
    int tid = threadIdx.x;
    int tx = tid & 15, ty = tid >> 4;
    // load Q tile transposed: Qs[d][t]
    {
        int r = tid >> 4, d4 = (tid & 15) * 4;
        #pragma unroll
        for (int j = 0; j < 4; j++) {
            int tt = r + j * 16;
            float4 qv = *(const float4*)(qb + (size_t)(t0 + tt) * kD + d4);
            Qs[d4 + 0][tt] = qv.x; Qs[d4 + 1][tt] = qv.y;
            Qs[d4 + 2][tt] = qv.z; Qs[d4 + 3][tt] = qv.w;
        }
    }
    float m_i[4], l_i[4], acc[4][4];
    #pragma unroll
    for (int i = 0; i < 4; i++) {
        m_i[i] = -INFINITY; l_i[i] = 0.f;
        #pragma unroll
        for (int j = 0; j < 4; j++) acc[i][j] = 0.f;
    }
    for (int s0 = 0; s0 < kT; s0 += 64) {
        __syncthreads();   // previous iteration consumers done with KPs/Vs
        {
            int r = tid >> 4, d4 = (tid & 15) * 4;
            #pragma unroll
            for (int j = 0; j < 4; j++) {
                int ss = r + j * 16;
                float4 kv = *(const float4*)(kb + (size_t)(s0 + ss) * kD + d4);
                KPs[d4 + 0][ss] = kv.x; KPs[d4 + 1][ss] = kv.y;
                KPs[d4 + 2][ss] = kv.z; KPs[d4 + 3][ss] = kv.w;
                float4 vv = *(const float4*)(vb + (size_t)(s0 + ss) * kD + d4);
                *(float4*)&Vs[ss][d4] = vv;
            }
            if (tid < 64) padf[tid] = pad[b * kT + s0 + tid];
        }
        __syncthreads();
        // scores: S = Q K^T for this 64x64 tile
        float sc[4][4] = {};
        #pragma unroll 8
        for (int d = 0; d < 64; d++) {
            float4 qv = *(const float4*)&Qs[d][ty * 4];
            float4 kv = *(const float4*)&KPs[d][tx * 4];
            float qa[4] = {qv.x, qv.y, qv.z, qv.w};
            float ka[4] = {kv.x, kv.y, kv.z, kv.w};
            #pragma unroll
            for (int i = 0; i < 4; i++)
                #pragma unroll
                for (int j = 0; j < 4; j++)
                    sc[i][j] += qa[i] * ka[j];
        }
        // mask + scale (padding override LAST, as in reference)
        #pragma unroll
        for (int i = 0; i < 4; i++) {
            int t = t0 + ty * 4 + i;
            #pragma unroll
            for (int j = 0; j < 4; j++) {
                int s = s0 + tx * 4 + j;
                float xv = sc[i][j] * 0.03125f;   // C^-0.5
                if (s > t) xv = -INFINITY;
                if (padf[tx * 4 + j]) xv = -1e9f;
                sc[i][j] = xv;
            }
        }
        // online softmax update (row groups = 16 consecutive lanes)
        float alpha[4];
        #pragma unroll
        for (int i = 0; i < 4; i++) {
            float mt = fmaxf(fmaxf(sc[i][0], sc[i][1]), fmaxf(sc[i][2], sc[i][3]));
            #pragma unroll
            for (int off = 1; off < 16; off <<= 1) mt = fmaxf(mt, __shfl_xor(mt, off));
            float mn = fmaxf(m_i[i], mt);
            alpha[i] = __expf(m_i[i] - mn);
            m_i[i] = mn;
            float rs = 0.f;
            #pragma unroll
            for (int j = 0; j < 4; j++) {
                sc[i][j] = __expf(sc[i][j] - mn);
                rs += sc[i][j];
            }
            #pragma unroll
            for (int off = 1; off < 16; off <<= 1) rs += __shfl_xor(rs, off);
            l_i[i] = l_i[i] * alpha[i] + rs;
            #pragma unroll
            for (int j = 0; j < 4; j++) acc[i][j] *= alpha[i];
        }
        __syncthreads();   // everyone done reading KPs (K) -> reuse as P
        #pragma unroll
        for (int j = 0; j < 4; j++) {
            float4 pv = make_float4(sc[0][j], sc[1][j], sc[2][j], sc[3][j]);
            *(float4*)&KPs[tx * 4 + j][ty * 4] = pv;
        }
        __syncthreads();
        // O += P V
        #pragma unroll 8
        for (int s = 0; s < 64; s++) {
            float4 pv = *(const float4*)&KPs[s][ty * 4];
            float4 vv = *(const float4*)&Vs[s][tx * 4];
            float pa[4] = {pv.x, pv.y, pv.z, pv.w};
            float va[4] = {vv.x, vv.y, vv.z, vv.w};
            #pragma unroll
            for (int i = 0; i < 4; i++)
                #pragma unroll
                for (int j = 0; j < 4; j++)
                    acc[i][j] += pa[i] * va[j];
        }
    }
    // epilogue: normalize and write concat-head layout (B,T,C)
    #pragma unroll
    for (int i = 0; i < 4; i++) {
        float inv = 1.0f / l_i[i];
        int t = t0 + ty * 4 + i;
        float4 o = make_float4(acc[i][0] * inv, acc[i][1] * inv,
                               acc[i][2] * inv, acc[i][3] * inv);
        *(float4*)(out + ((size_t)(b * kT + t)) * kC + head * kD + tx * 4) = o;
    }
}

// ---------------------------------------------------------------------------
// Generic GEMM: C = A(MxK) * B(KxN) + bias, optional ReLU. Row-major all.
// Tile 64x64x16, 256 threads, 4x4 per thread. grid = (N/64, M/64)
// ---------------------------------------------------------------------------
__global__ __launch_bounds__(256) void gemm_kernel(const float* __restrict__ A,
                                                   const float* __restrict__ Bm,
                                                   const float* __restrict__ bias,
                                                   float* __restrict__ Cc,
                                                   int M, int N, int K, int relu) {
    __shared__ float As[16][64];
    __shared__ float Bs[16][68];
    int tid = threadIdx.x;
    int bm = blockIdx.y * 64;
    int bn = blockIdx.x * 64;
    int tx = tid & 15, ty = tid >> 4;
    float acc[4][4] = {};
    for (int k0 = 0; k0 < K; k0 += 16) {
        {
            int r = tid >> 2, c4 = (tid & 3) * 4;
            float4 a = *(const float4*)(A + (size_t)(bm + r) * K + k0 + c4);
            As[c4 + 0][r] = a.x; As[c4 + 1][r] = a.y;
            As[c4 + 2][r] = a.z; As[c4 + 3][r] = a.w;
        }
        {
            int r = tid >> 4, c4 = (tid & 15) * 4;
            float4 b = *(const float4*)(Bm + (size_t)(k0 + r) * N + bn + c4);
            *(float4*)&Bs[r][c4] = b;
        }
        __syncthreads();
        #pragma unroll
        for (int kk = 0; kk < 16; kk++) {
            float4 av = *(const float4*)&As[kk][ty * 4];
            float4 bv = *(const float4*)&Bs[kk][tx * 4];
            float aa[4] = {av.x, av.y, av.z, av.w};
            float bb[4] = {bv.x, bv.y, bv.z, bv.w};
            #pragma unroll
            for (int i = 0; i < 4; i++)
                #pragma unroll
                for (int j = 0; j < 4; j++)
                    acc[i][j] += aa[i] * bb[j];
        }
        __syncthreads();
    }
    float4 bb = *(const float4*)(bias + bn + tx * 4);
    #pragma unroll
    for (int i = 0; i < 4; i++) {
        int m = bm + ty * 4 + i;
        float4 o = make_float4(acc[i][0] + bb.x, acc[i][1] + bb.y,
                               acc[i][2] + bb.z, acc[i][3] + bb.w);
        if (relu) {
            o.x = fmaxf(o.x, 0.f); o.y = fmaxf(o.y, 0.f);
            o.z = fmaxf(o.z, 0.f); o.w = fmaxf(o.w, 0.f);
        }
        *(float4*)(Cc + (size_t)m * N + bn + tx * 4) = o;
    }
}

// ---------------------------------------------------------------------------
extern "C" void kernel_launch(void* const* d_in, const int* in_sizes, int n_in,
                              void* d_out, int out_size, void* d_ws, size_t ws_size,
                              hipStream_t stream) {
    (void)in_sizes; (void)n_in; (void)out_size; (void)ws_size;
    const float* x    = (const float*)d_in[0];
    const int*   pad  = (const int*)d_in[1];
    const float* Wq   = (const float*)d_in[2];
    const float* Wk   = (const float*)d_in[3];
    const float* Wv   = (const float*)d_in[4];
    const float* Wo   = (const float*)d_in[5];
    const float* bo   = (const float*)d_in[6];
    const float* ln1g = (const float*)d_in[7];
    const float* ln1b = (const float*)d_in[8];
    const float* ln2g = (const float*)d_in[9];
    const float* ln2b = (const float*)d_in[10];
    const float* W1   = (const float*)d_in[11];
    const float* b1   = (const float*)d_in[12];
    const float* W2   = (const float*)d_in[13];
    const float* b2   = (const float*)d_in[14];
    float* out = (float*)d_out;
    float* ws = (float*)d_ws;

    const size_t NE = (size_t)kBT * kC;   // 4M floats = 16 MB
    float* h    = ws + 0 * NE;            // [0,1)NE
    float* qbuf = ws + 1 * NE;            // [1,2)
    float* kbuf = ws + 2 * NE;            // [2,3)
    float* vbuf = ws + 3 * NE;            // [3,4)
    float* attn = ws + 4 * NE;            // [4,5)
    float* proj = ws + 0 * NE;            // reuse h (dead after QKV)
    float* h2   = ws + 5 * NE;            // [5,6)
    float* ffn1 = ws + 1 * NE;            // [1,5) 4*NE -- q/k/v/attn dead
    // peak: 6*NE floats = 96 MB

    ln_kernel<<<kBT, 256, 0, stream>>>(x, ln1g, ln1b, h);
    qkv_kernel<<<dim3(48, 64), 256, 0, stream>>>(h, Wq, Wk, Wv, qbuf, kbuf, vbuf);
    attn_kernel<<<dim3(kT / 64, kB * kH), 256, 0, stream>>>(qbuf, kbuf, vbuf, pad, attn);
    gemm_kernel<<<dim3(kC / 64, kBT / 64), 256, 0, stream>>>(attn, Wo, bo, proj,
                                                             kBT, kC, kC, 0);
    ln_kernel<<<kBT, 256, 0, stream>>>(proj, ln2g, ln2b, h2);
    gemm_kernel<<<dim3(kF / 64, kBT / 64), 256, 0, stream>>>(h2, W1, b1, ffn1,
                                                             kBT, kF, kC, 1);
    gemm_kernel<<<dim3(kC / 64, kBT / 64), 256, 0, stream>>>(ffn1, W2, b2, out,
                                                             kBT, kC, kF, 0);
}

// Round 4
// 527.772 us; speedup vs baseline: 3.3266x; 3.3266x over previous
//
#include <hip/hip_runtime.h>
#include <hip/hip_bf16.h>
#include <math.h>

// Problem constants
constexpr int kB = 4;
constexpr int kT = 1024;
constexpr int kC = 1024;
constexpr int kH = 16;
constexpr int kD = 64;
constexpr int kF = 4096;
constexpr int kBT = kB * kT;

typedef __attribute__((ext_vector_type(8))) short short8;   // bf16x8 MFMA frag (4 VGPRs)
typedef __attribute__((ext_vector_type(4))) float f32x4;    // MFMA acc frag

__device__ __forceinline__ unsigned short f2bf(float f) {
    __hip_bfloat16 h = __float2bfloat16(f);
    return __builtin_bit_cast(unsigned short, h);
}
__device__ __forceinline__ float bf2f(unsigned short u) {
    return __bfloat162float(__builtin_bit_cast(__hip_bfloat16, u));
}

// ---------------------------------------------------------------------------
// LayerNorm -> bf16 out. One block per row (C=1024), 256 threads.
// ---------------------------------------------------------------------------
__global__ __launch_bounds__(256) void ln_bf16_kernel(const float* __restrict__ x,
                                                      const float* __restrict__ g,
                                                      const float* __restrict__ bta,
                                                      unsigned short* __restrict__ out) {
    int row = blockIdx.x;
    int t = threadIdx.x;
    float4 xv = ((const float4*)(x + (size_t)row * kC))[t];
    float s  = xv.x + xv.y + xv.z + xv.w;
    float sq = xv.x * xv.x + xv.y * xv.y + xv.z * xv.z + xv.w * xv.w;
    #pragma unroll
    for (int off = 32; off; off >>= 1) {
        s  += __shfl_xor(s, off);
        sq += __shfl_xor(sq, off);
    }
    __shared__ float sb[8];
    int wid = t >> 6, lane = t & 63;
    if (lane == 0) { sb[wid] = s; sb[4 + wid] = sq; }
    __syncthreads();
    s  = sb[0] + sb[1] + sb[2] + sb[3];
    sq = sb[4] + sb[5] + sb[6] + sb[7];
    float mean = s * (1.0f / kC);
    float var  = sq * (1.0f / kC) - mean * mean;
    float rs = rsqrtf(var + 1e-5f);
    float4 gv = ((const float4*)g)[t];
    float4 bv = ((const float4*)bta)[t];
    ushort4 o;
    o.x = f2bf((xv.x - mean) * rs * gv.x + bv.x);
    o.y = f2bf((xv.y - mean) * rs * gv.y + bv.y);
    o.z = f2bf((xv.z - mean) * rs * gv.z + bv.z);
    o.w = f2bf((xv.w - mean) * rs * gv.w + bv.w);
    *(ushort4*)(out + (size_t)row * kC + t * 4) = o;
}

// ---------------------------------------------------------------------------
// Transpose fp32 (R x C) -> bf16 (C x R), batched. grid (R/64, C/64, batch).
// ---------------------------------------------------------------------------
__global__ __launch_bounds__(256) void transpose_w_kernel(const float* __restrict__ src,
                                                          unsigned short* __restrict__ dst,
                                                          int R, int C) {
    __shared__ float tile[64][65];
    src += (size_t)blockIdx.z * R * C;
    dst += (size_t)blockIdx.z * R * C;
    int r0 = blockIdx.x * 64, c0 = blockIdx.y * 64;
    int tid = threadIdx.x;
    int tr = tid >> 4, tc4 = (tid & 15) * 4;
    #pragma unroll
    for (int p = 0; p < 4; p++) {
        float4 v = *(const float4*)(src + (size_t)(r0 + tr + p * 16) * C + c0 + tc4);
        tile[tr + p * 16][tc4 + 0] = v.x;
        tile[tr + p * 16][tc4 + 1] = v.y;
        tile[tr + p * 16][tc4 + 2] = v.z;
        tile[tr + p * 16][tc4 + 3] = v.w;
    }
    __syncthreads();
    #pragma unroll
    for (int p = 0; p < 4; p++) {
        int c = tr + p * 16;
        ushort4 o;
        o.x = f2bf(tile[tc4 + 0][c]);
        o.y = f2bf(tile[tc4 + 1][c]);
        o.z = f2bf(tile[tc4 + 2][c]);
        o.w = f2bf(tile[tc4 + 3][c]);
        *(ushort4*)(dst + (size_t)(c0 + c) * R + r0 + tc4) = o;
    }
}

// ---------------------------------------------------------------------------
// Extract V from qkv buffer and transpose to (B,H,D,T) bf16. grid (T/64, B*H).
// ---------------------------------------------------------------------------
__global__ __launch_bounds__(256) void transpose_v_kernel(const unsigned short* __restrict__ qkv,
                                                          unsigned short* __restrict__ vt) {
    __shared__ unsigned short tile[64][68];
    int bh = blockIdx.y, b = bh >> 4, h = bh & 15;
    int t0 = blockIdx.x * 64;
    int tid = threadIdx.x;
    int tr = tid >> 4, tc4 = (tid & 15) * 4;
    #pragma unroll
    for (int p = 0; p < 4; p++) {
        int t = t0 + tr + p * 16;
        ushort4 v = *(const ushort4*)(qkv + ((size_t)(b * kT + t)) * 3072 + 2048 + h * 64 + tc4);
        *(ushort4*)&tile[tr + p * 16][tc4] = v;
    }
    __syncthreads();
    #pragma unroll
    for (int p = 0; p < 4; p++) {
        int d = tr + p * 16;
        ushort4 o;
        o.x = tile[tc4 + 0][d];
        o.y = tile[tc4 + 1][d];
        o.z = tile[tc4 + 2][d];
        o.w = tile[tc4 + 3][d];
        *(ushort4*)(vt + ((size_t)(bh * 64 + d)) * kT + t0 + tc4) = o;
    }
}

// ---------------------------------------------------------------------------
// Pad scan: Npad[b] and first_unpad[b] = min{t : pad==0} (1024 if none).
// ---------------------------------------------------------------------------
__global__ __launch_bounds__(256) void padscan_kernel(const int* __restrict__ pad,
                                                      int* __restrict__ npad,
                                                      int* __restrict__ fu) {
    int b = blockIdx.x, tid = threadIdx.x;
    int cnt = 0, f = kT;
    for (int t = tid; t < kT; t += 256) {
        int p = pad[b * kT + t];
        cnt += p;
        if (!p) f = min(f, t);
    }
    __shared__ int sc[256], sf[256];
    sc[tid] = cnt; sf[tid] = f;
    __syncthreads();
    for (int o = 128; o; o >>= 1) {
        if (tid < o) { sc[tid] += sc[tid + o]; sf[tid] = min(sf[tid], sf[tid + o]); }
        __syncthreads();
    }
    if (tid == 0) { npad[b] = sc[0]; fu[b] = sf[0]; }
}

// ---------------------------------------------------------------------------
// meanv[b][h][d] = mean over padded t of V. grid (B*H), 256 threads.
// ---------------------------------------------------------------------------
__global__ __launch_bounds__(256) void meanv_kernel(const unsigned short* __restrict__ vt,
                                                    const int* __restrict__ pad,
                                                    const int* __restrict__ npad,
                                                    float* __restrict__ meanv) {
    int bh = blockIdx.x, b = bh >> 4;
    int tid = threadIdx.x, d = tid >> 2, seg = tid & 3;
    const unsigned short* row = vt + ((size_t)bh * 64 + d) * kT + seg * 256;
    const int* pr = pad + b * kT + seg * 256;
    float s = 0.f;
    for (int t = 0; t < 256; ++t)
        if (pr[t]) s += bf2f(row[t]);
    __shared__ float red[256];
    red[tid] = s;
    __syncthreads();
    if (seg == 0) {
        float tot = red[tid] + red[tid + 1] + red[tid + 2] + red[tid + 3];
        int np = npad[b];
        meanv[bh * 64 + d] = np > 0 ? tot / (float)np : 0.f;
    }
}

// ---------------------------------------------------------------------------
// Fixup: rows t < first_unpad[b] attend uniformly to ALL padded keys.
// ---------------------------------------------------------------------------
__global__ __launch_bounds__(256) void fixup_kernel(unsigned short* __restrict__ attnb,
                                                    const float* __restrict__ meanv,
                                                    const int* __restrict__ fu) {
    int b = blockIdx.x, tid = threadIdx.x;
    int f = fu[b];
    int c = tid * 4;
    ushort4 u;
    u.x = f2bf(meanv[b * kC + c + 0]);
    u.y = f2bf(meanv[b * kC + c + 1]);
    u.z = f2bf(meanv[b * kC + c + 2]);
    u.w = f2bf(meanv[b * kC + c + 3]);
    for (int t = 0; t < f; ++t)
        *(ushort4*)(attnb + ((size_t)(b * kT + t)) * kC + c) = u;
}

// ---------------------------------------------------------------------------
// MFMA flash attention, causal range only. grid (T/64, B*H), 256 thr (4 waves).
// Wave w owns q-rows [t0+16w, t0+16w+16). S^T = K Q^T per 32-s chunk; online
// softmax in C-layout (q = lane&15); P via per-wave LDS; PV against global V^T.
// Padded keys contribute exp(-1e9 - m) == 0 exactly in fp32 for any row with
// a finite max; rows whose visible keys are ALL padded are overwritten by
// fixup_kernel (uniform attention over all padded keys, incl. future).
// ---------------------------------------------------------------------------
__global__ __launch_bounds__(256) void attn_kernel(const unsigned short* __restrict__ qkv,
                                                   const unsigned short* __restrict__ vt,
                                                   const int* __restrict__ pad,
                                                   unsigned short* __restrict__ outb) {
    __shared__ char padc[kT];
    __shared__ __align__(16) unsigned short Ps[4][16][40];  // per-wave P tile
    const int tid = threadIdx.x;
    const int bh = blockIdx.y, b = bh >> 4, h = bh & 15;
    const int t0 = blockIdx.x * 64;
    const int wv = tid >> 6, lane = tid & 63;
    const int lm = lane & 15, lk = lane >> 4;
    for (int i = tid; i < kT; i += 256) padc[i] = (char)pad[b * kT + i];
    __syncthreads();

    const int qrow = t0 + wv * 16 + lm;
    const size_t qoff = ((size_t)(b * kT + qrow)) * 3072 + h * 64 + lk * 8;
    short8 bq0 = *(const short8*)(qkv + qoff);
    short8 bq1 = *(const short8*)(qkv + qoff + 32);

    f32x4 o[4];
    #pragma unroll
    for (int dt = 0; dt < 4; dt++) o[dt] = (f32x4){0.f, 0.f, 0.f, 0.f};
    float m_i = -__builtin_inff(), l_i = 0.f;
    const int send = t0 + wv * 16 + 15;

    for (int s0 = 0; s0 <= send; s0 += 32) {
        // --- scores S^T(32s x 16q) = K . Q^T ---
        const size_t k0off = ((size_t)(b * kT + s0 + lm)) * 3072 + 1024 + h * 64 + lk * 8;
        short8 ka00 = *(const short8*)(qkv + k0off);
        short8 ka01 = *(const short8*)(qkv + k0off + 32);
        short8 ka10 = *(const short8*)(qkv + k0off + 16 * 3072);
        short8 ka11 = *(const short8*)(qkv + k0off + 16 * 3072 + 32);
        f32x4 c0 = (f32x4){0.f, 0.f, 0.f, 0.f};
        f32x4 c1 = (f32x4){0.f, 0.f, 0.f, 0.f};
        c0 = __builtin_amdgcn_mfma_f32_16x16x32_bf16(ka00, bq0, c0, 0, 0, 0);
        c0 = __builtin_amdgcn_mfma_f32_16x16x32_bf16(ka01, bq1, c0, 0, 0, 0);
        c1 = __builtin_amdgcn_mfma_f32_16x16x32_bf16(ka10, bq0, c1, 0, 0, 0);
        c1 = __builtin_amdgcn_mfma_f32_16x16x32_bf16(ka11, bq1, c1, 0, 0, 0);
        // --- mask + scale (pad override last, as in reference) ---
        float x[8];
        #pragma unroll
        for (int r = 0; r < 4; r++) {
            int s = s0 + lk * 4 + r;
            float v = c0[r] * 0.03125f;
            if (s > qrow) v = -__builtin_inff();
            if (padc[s]) v = -1e9f;
            x[r] = v;
        }
        #pragma unroll
        for (int r = 0; r < 4; r++) {
            int s = s0 + 16 + lk * 4 + r;
            float v = c1[r] * 0.03125f;
            if (s > qrow) v = -__builtin_inff();
            if (padc[s]) v = -1e9f;
            x[4 + r] = v;
        }
        // --- online softmax (col q = lm; reduce over lane^16, lane^32) ---
        float mt = x[0];
        #pragma unroll
        for (int i = 1; i < 8; i++) mt = fmaxf(mt, x[i]);
        mt = fmaxf(mt, __shfl_xor(mt, 16));
        mt = fmaxf(mt, __shfl_xor(mt, 32));
        float mn = fmaxf(m_i, mt);
        float alpha = __expf(m_i - mn);
        float p[8], rs = 0.f;
        #pragma unroll
        for (int i = 0; i < 8; i++) { p[i] = __expf(x[i] - mn); rs += p[i]; }
        rs += __shfl_xor(rs, 16);
        rs += __shfl_xor(rs, 32);
        l_i = l_i * alpha + rs;
        m_i = mn;
        // --- P -> LDS [q][s] ---
        ushort4 u0, u1;
        u0.x = f2bf(p[0]); u0.y = f2bf(p[1]); u0.z = f2bf(p[2]); u0.w = f2bf(p[3]);
        u1.x = f2bf(p[4]); u1.y = f2bf(p[5]); u1.z = f2bf(p[6]); u1.w = f2bf(p[7]);
        *(ushort4*)&Ps[wv][lm][lk * 4] = u0;
        *(ushort4*)&Ps[wv][lm][16 + lk * 4] = u1;
        // --- rescale acc (rows q' = lk*4+r) ---
        float ar0 = __shfl(alpha, lk * 4 + 0);
        float ar1 = __shfl(alpha, lk * 4 + 1);
        float ar2 = __shfl(alpha, lk * 4 + 2);
        float ar3 = __shfl(alpha, lk * 4 + 3);
        #pragma unroll
        for (int dt = 0; dt < 4; dt++) {
            o[dt][0] *= ar0; o[dt][1] *= ar1; o[dt][2] *= ar2; o[dt][3] *= ar3;
        }
        // --- O += P V (A = P from LDS, B = V^T from global) ---
        short8 ap = *(const short8*)&Ps[wv][lm][lk * 8];
        #pragma unroll
        for (int dt = 0; dt < 4; dt++) {
            short8 bv = *(const short8*)(vt + ((size_t)(bh * 64 + dt * 16 + lm)) * kT + s0 + lk * 8);
            o[dt] = __builtin_amdgcn_mfma_f32_16x16x32_bf16(ap, bv, o[dt], 0, 0, 0);
        }
    }
    // --- epilogue: normalize, write (B,T,C) bf16 ---
    float inv[4];
    #pragma unroll
    for (int r = 0; r < 4; r++) {
        float lr = __shfl(l_i, lk * 4 + r);
        inv[r] = 1.0f / lr;
    }
    #pragma unroll
    for (int dt = 0; dt < 4; dt++)
        #pragma unroll
        for (int r = 0; r < 4; r++) {
            int trow = t0 + wv * 16 + lk * 4 + r;
            outb[((size_t)(b * kT + trow)) * kC + h * 64 + dt * 16 + lm] = f2bf(o[dt][r] * inv[r]);
        }
}

// ---------------------------------------------------------------------------
// bf16 MFMA GEMM: C(MxN) = A(MxK) . Bt(NxK)^T, fp32 acc.
// Tile TM x TN, BK=32, 256 threads (4 waves, 2x2).
// Staging via explicit short8 loads + ds_write_b128 (m93-style; bisect round:
// global_load_lds removed as the container-kill suspect).
// ---------------------------------------------------------------------------
template<int TM, int TN>
__global__ __launch_bounds__(256) void gemm_bt(const unsigned short* __restrict__ A,
                                               const unsigned short* __restrict__ Bt,
                                               const float* __restrict__ bias,
                                               float* __restrict__ Cf,
                                               unsigned short* __restrict__ Cb,
                                               int N, int K, int relu) {
    constexpr int AI = TM / 32, BJ = TN / 32;
    __shared__ __align__(16) unsigned short As[TM * 32];
    __shared__ __align__(16) unsigned short Bs[TN * 32];
    const int tid = threadIdx.x;
    const int wv = tid >> 6, lane = tid & 63;
    const int lm = lane & 15, lk = lane >> 4;
    const int srow = tid >> 2, sk8 = (tid & 3) * 8;   // staging: row 0..63, k-chunk
    const int bm = blockIdx.y * TM, bn = blockIdx.x * TN;
    const int wm = (wv >> 1) * (TM / 2), wn = (wv & 1) * (TN / 2);
    f32x4 acc[AI][BJ];
    #pragma unroll
    for (int i = 0; i < AI; i++)
        #pragma unroll
        for (int j = 0; j < BJ; j++) acc[i][j] = (f32x4){0.f, 0.f, 0.f, 0.f};

    for (int k0 = 0; k0 < K; k0 += 32) {
        #pragma unroll
        for (int i = 0; i < TM / 64; i++) {
            short8 v = *(const short8*)(A + (size_t)(bm + srow + i * 64) * K + k0 + sk8);
            *(short8*)&As[(srow + i * 64) * 32 + sk8] = v;
        }
        #pragma unroll
        for (int i = 0; i < TN / 64; i++) {
            short8 v = *(const short8*)(Bt + (size_t)(bn + srow + i * 64) * K + k0 + sk8);
            *(short8*)&Bs[(srow + i * 64) * 32 + sk8] = v;
        }
        __syncthreads();
        short8 a[AI], bfr[BJ];
        #pragma unroll
        for (int i = 0; i < AI; i++)
            a[i] = *(const short8*)(As + (wm + i * 16 + lm) * 32 + lk * 8);
        #pragma unroll
        for (int j = 0; j < BJ; j++)
            bfr[j] = *(const short8*)(Bs + (wn + j * 16 + lm) * 32 + lk * 8);
        #pragma unroll
        for (int i = 0; i < AI; i++)
            #pragma unroll
            for (int j = 0; j < BJ; j++)
                acc[i][j] = __builtin_amdgcn_mfma_f32_16x16x32_bf16(a[i], bfr[j], acc[i][j], 0, 0, 0);
        __syncthreads();
    }
    #pragma unroll
    for (int j = 0; j < BJ; j++) {
        int col = bn + wn + j * 16 + lm;
        float bj = bias ? bias[col] : 0.f;
        #pragma unroll
        for (int i = 0; i < AI; i++) {
            #pragma unroll
            for (int r = 0; r < 4; r++) {
                int row = bm + wm + i * 16 + lk * 4 + r;
                float v = acc[i][j][r] + bj;
                if (relu) v = fmaxf(v, 0.f);
                if (Cf) Cf[(size_t)row * N + col] = v;
                else    Cb[(size_t)row * N + col] = f2bf(v);
            }
        }
    }
}

// ---------------------------------------------------------------------------
extern "C" void kernel_launch(void* const* d_in, const int* in_sizes, int n_in,
                              void* d_out, int out_size, void* d_ws, size_t ws_size,
                              hipStream_t stream) {
    (void)in_sizes; (void)n_in; (void)out_size; (void)ws_size;
    const float* x    = (const float*)d_in[0];
    const int*   pad  = (const int*)d_in[1];
    const float* Wq   = (const float*)d_in[2];
    const float* Wk   = (const float*)d_in[3];
    const float* Wv   = (const float*)d_in[4];
    const float* Wo   = (const float*)d_in[5];
    const float* bo   = (const float*)d_in[6];
    const float* ln1g = (const float*)d_in[7];
    const float* ln1b = (const float*)d_in[8];
    const float* ln2g = (const float*)d_in[9];
    const float* ln2b = (const float*)d_in[10];
    const float* W1   = (const float*)d_in[11];
    const float* b1   = (const float*)d_in[12];
    const float* W2   = (const float*)d_in[13];
    const float* b2   = (const float*)d_in[14];
    float* out = (float*)d_out;
    char* w = (char*)d_ws;

    constexpr size_t MB = 1024 * 1024;
    unsigned short* qkv   = (unsigned short*)(w + 0);        // 24 MB bf16 (BT x 3072)
    float*          proj  = (float*)(w + 0);                 // 16 MB fp32 (alias; qkv dead)
    unsigned short* h2    = (unsigned short*)(w + 16 * MB);  // 8 MB
    unsigned short* h     = (unsigned short*)(w + 24 * MB);  // 8 MB
    unsigned short* ffn1  = (unsigned short*)(w + 24 * MB);  // 32 MB (alias; h/wqkvt/vt/attn dead)
    unsigned short* wqkvt = (unsigned short*)(w + 32 * MB);  // 6 MB
    unsigned short* vt    = (unsigned short*)(w + 40 * MB);  // 8 MB
    unsigned short* attnb = (unsigned short*)(w + 48 * MB);  // 8 MB
    unsigned short* w1t   = (unsigned short*)(w + 56 * MB);  // 8 MB
    unsigned short* w2t   = (unsigned short*)(w + 64 * MB);  // 8 MB
    unsigned short* wot   = (unsigned short*)(w + 72 * MB);  // 2 MB
    float*          meanv = (float*)(w + 74 * MB);           // 16 KB
    int*            npad  = (int*)(w + 74 * MB + 65536);
    int*            fu    = (int*)(w + 74 * MB + 65536 + 64);

    // weight conversions (fp32 -> bf16, transposed to N x K)
    transpose_w_kernel<<<dim3(16, 1, 16), 256, 0, stream>>>(Wq, wqkvt,               kC, kD);
    transpose_w_kernel<<<dim3(16, 1, 16), 256, 0, stream>>>(Wk, wqkvt + 1024 * 1024, kC, kD);
    transpose_w_kernel<<<dim3(16, 1, 16), 256, 0, stream>>>(Wv, wqkvt + 2048 * 1024, kC, kD);
    transpose_w_kernel<<<dim3(16, 16, 1), 256, 0, stream>>>(Wo, wot, kC, kC);
    transpose_w_kernel<<<dim3(16, 64, 1), 256, 0, stream>>>(W1, w1t, kC, kF);
    transpose_w_kernel<<<dim3(64, 16, 1), 256, 0, stream>>>(W2, w2t, kF, kC);

    ln_bf16_kernel<<<kBT, 256, 0, stream>>>(x, ln1g, ln1b, h);
    gemm_bt<128, 128><<<dim3(24, 32), 256, 0, stream>>>(h, wqkvt, nullptr, nullptr, qkv,
                                                        3072, kC, 0);
    transpose_v_kernel<<<dim3(16, 64), 256, 0, stream>>>(qkv, vt);
    padscan_kernel<<<kB, 256, 0, stream>>>(pad, npad, fu);
    meanv_kernel<<<kB * kH, 256, 0, stream>>>(vt, pad, npad, meanv);
    attn_kernel<<<dim3(16, 64), 256, 0, stream>>>(qkv, vt, pad, attnb);
    fixup_kernel<<<kB, 256, 0, stream>>>(attnb, meanv, fu);
    gemm_bt<128, 64><<<dim3(16, 32), 256, 0, stream>>>(attnb, wot, bo, proj, nullptr,
                                                       kC, kC, 0);
    ln_bf16_kernel<<<kBT, 256, 0, stream>>>(proj, ln2g, ln2b, h2);
    gemm_bt<128, 128><<<dim3(32, 32), 256, 0, stream>>>(h2, w1t, b1, nullptr, ffn1,
                                                        kF, kC, 1);
    gemm_bt<128, 64><<<dim3(16, 32), 256, 0, stream>>>(ffn1, w2t, b2, out, nullptr,
                                                       kC, kF, 0);
}

// Round 5
// 511.678 us; speedup vs baseline: 3.4313x; 1.0315x over previous
//
#include <hip/hip_runtime.h>
#include <hip/hip_bf16.h>
#include <math.h>

// Problem constants
constexpr int kB = 4;
constexpr int kT = 1024;
constexpr int kC = 1024;
constexpr int kH = 16;
constexpr int kD = 64;
constexpr int kF = 4096;
constexpr int kBT = kB * kT;
constexpr int kSplit = 4;   // attention s-splits

typedef __attribute__((ext_vector_type(8))) short short8;   // bf16x8 MFMA frag (4 VGPRs)
typedef __attribute__((ext_vector_type(4))) float f32x4;    // MFMA acc frag

__device__ __forceinline__ unsigned short f2bf(float f) {
    __hip_bfloat16 h = __float2bfloat16(f);
    return __builtin_bit_cast(unsigned short, h);
}
__device__ __forceinline__ float bf2f(unsigned short u) {
    return __bfloat162float(__builtin_bit_cast(__hip_bfloat16, u));
}

// NOTE: __builtin_amdgcn_global_load_lds is BANNED in this harness — it
// deterministically killed the MI355X container (rounds 2-3 bisect).

// ---------------------------------------------------------------------------
// LayerNorm -> bf16 out. One block per row (C=1024), 256 threads.
// ---------------------------------------------------------------------------
__global__ __launch_bounds__(256) void ln_bf16_kernel(const float* __restrict__ x,
                                                      const float* __restrict__ g,
                                                      const float* __restrict__ bta,
                                                      unsigned short* __restrict__ out) {
    int row = blockIdx.x;
    int t = threadIdx.x;
    float4 xv = ((const float4*)(x + (size_t)row * kC))[t];
    float s  = xv.x + xv.y + xv.z + xv.w;
    float sq = xv.x * xv.x + xv.y * xv.y + xv.z * xv.z + xv.w * xv.w;
    #pragma unroll
    for (int off = 32; off; off >>= 1) {
        s  += __shfl_xor(s, off);
        sq += __shfl_xor(sq, off);
    }
    __shared__ float sb[8];
    int wid = t >> 6, lane = t & 63;
    if (lane == 0) { sb[wid] = s; sb[4 + wid] = sq; }
    __syncthreads();
    s  = sb[0] + sb[1] + sb[2] + sb[3];
    sq = sb[4] + sb[5] + sb[6] + sb[7];
    float mean = s * (1.0f / kC);
    float var  = sq * (1.0f / kC) - mean * mean;
    float rs = rsqrtf(var + 1e-5f);
    float4 gv = ((const float4*)g)[t];
    float4 bv = ((const float4*)bta)[t];
    ushort4 o;
    o.x = f2bf((xv.x - mean) * rs * gv.x + bv.x);
    o.y = f2bf((xv.y - mean) * rs * gv.y + bv.y);
    o.z = f2bf((xv.z - mean) * rs * gv.z + bv.z);
    o.w = f2bf((xv.w - mean) * rs * gv.w + bv.w);
    *(ushort4*)(out + (size_t)row * kC + t * 4) = o;
}

// ---------------------------------------------------------------------------
// Transpose fp32 (R x C) -> bf16 (C x R), batched. grid (R/64, C/64, batch).
// ---------------------------------------------------------------------------
__global__ __launch_bounds__(256) void transpose_w_kernel(const float* __restrict__ src,
                                                          unsigned short* __restrict__ dst,
                                                          int R, int C) {
    __shared__ float tile[64][65];
    src += (size_t)blockIdx.z * R * C;
    dst += (size_t)blockIdx.z * R * C;
    int r0 = blockIdx.x * 64, c0 = blockIdx.y * 64;
    int tid = threadIdx.x;
    int tr = tid >> 4, tc4 = (tid & 15) * 4;
    #pragma unroll
    for (int p = 0; p < 4; p++) {
        float4 v = *(const float4*)(src + (size_t)(r0 + tr + p * 16) * C + c0 + tc4);
        tile[tr + p * 16][tc4 + 0] = v.x;
        tile[tr + p * 16][tc4 + 1] = v.y;
        tile[tr + p * 16][tc4 + 2] = v.z;
        tile[tr + p * 16][tc4 + 3] = v.w;
    }
    __syncthreads();
    #pragma unroll
    for (int p = 0; p < 4; p++) {
        int c = tr + p * 16;
        ushort4 o;
        o.x = f2bf(tile[tc4 + 0][c]);
        o.y = f2bf(tile[tc4 + 1][c]);
        o.z = f2bf(tile[tc4 + 2][c]);
        o.w = f2bf(tile[tc4 + 3][c]);
        *(ushort4*)(dst + (size_t)(c0 + c) * R + r0 + tc4) = o;
    }
}

// ---------------------------------------------------------------------------
// Extract V from qkv buffer and transpose to (B,H,D,T) bf16. grid (T/64, B*H).
// ---------------------------------------------------------------------------
__global__ __launch_bounds__(256) void transpose_v_kernel(const unsigned short* __restrict__ qkv,
                                                          unsigned short* __restrict__ vt) {
    __shared__ unsigned short tile[64][68];
    int bh = blockIdx.y, b = bh >> 4, h = bh & 15;
    int t0 = blockIdx.x * 64;
    int tid = threadIdx.x;
    int tr = tid >> 4, tc4 = (tid & 15) * 4;
    #pragma unroll
    for (int p = 0; p < 4; p++) {
        int t = t0 + tr + p * 16;
        ushort4 v = *(const ushort4*)(qkv + ((size_t)(b * kT + t)) * 3072 + 2048 + h * 64 + tc4);
        *(ushort4*)&tile[tr + p * 16][tc4] = v;
    }
    __syncthreads();
    #pragma unroll
    for (int p = 0; p < 4; p++) {
        int d = tr + p * 16;
        ushort4 o;
        o.x = tile[tc4 + 0][d];
        o.y = tile[tc4 + 1][d];
        o.z = tile[tc4 + 2][d];
        o.w = tile[tc4 + 3][d];
        *(ushort4*)(vt + ((size_t)(bh * 64 + d)) * kT + t0 + tc4) = o;
    }
}

// ---------------------------------------------------------------------------
// Pad scan: Npad[b] and first_unpad[b] = min{t : pad==0} (1024 if none).
// ---------------------------------------------------------------------------
__global__ __launch_bounds__(256) void padscan_kernel(const int* __restrict__ pad,
                                                      int* __restrict__ npad,
                                                      int* __restrict__ fu) {
    int b = blockIdx.x, tid = threadIdx.x;
    int cnt = 0, f = kT;
    for (int t = tid; t < kT; t += 256) {
        int p = pad[b * kT + t];
        cnt += p;
        if (!p) f = min(f, t);
    }
    __shared__ int sc[256], sf[256];
    sc[tid] = cnt; sf[tid] = f;
    __syncthreads();
    for (int o = 128; o; o >>= 1) {
        if (tid < o) { sc[tid] += sc[tid + o]; sf[tid] = min(sf[tid], sf[tid + o]); }
        __syncthreads();
    }
    if (tid == 0) { npad[b] = sc[0]; fu[b] = sf[0]; }
}

// ---------------------------------------------------------------------------
// meanv[b][h][d] = mean over padded t of V. grid (B*H), 256 threads.
// ---------------------------------------------------------------------------
__global__ __launch_bounds__(256) void meanv_kernel(const unsigned short* __restrict__ vt,
                                                    const int* __restrict__ pad,
                                                    const int* __restrict__ npad,
                                                    float* __restrict__ meanv) {
    int bh = blockIdx.x, b = bh >> 4;
    int tid = threadIdx.x, d = tid >> 2, seg = tid & 3;
    const unsigned short* row = vt + ((size_t)bh * 64 + d) * kT + seg * 256;
    const int* pr = pad + b * kT + seg * 256;
    float s = 0.f;
    for (int t = 0; t < 256; ++t)
        if (pr[t]) s += bf2f(row[t]);
    __shared__ float red[256];
    red[tid] = s;
    __syncthreads();
    if (seg == 0) {
        float tot = red[tid] + red[tid + 1] + red[tid + 2] + red[tid + 3];
        int np = npad[b];
        meanv[bh * 64 + d] = np > 0 ? tot / (float)np : 0.f;
    }
}

// ---------------------------------------------------------------------------
// Fixup: rows t < first_unpad[b] attend uniformly to ALL padded keys.
// ---------------------------------------------------------------------------
__global__ __launch_bounds__(256) void fixup_kernel(unsigned short* __restrict__ attnb,
                                                    const float* __restrict__ meanv,
                                                    const int* __restrict__ fu) {
    int b = blockIdx.x, tid = threadIdx.x;
    int f = fu[b];
    int c = tid * 4;
    ushort4 u;
    u.x = f2bf(meanv[b * kC + c + 0]);
    u.y = f2bf(meanv[b * kC + c + 1]);
    u.z = f2bf(meanv[b * kC + c + 2]);
    u.w = f2bf(meanv[b * kC + c + 3]);
    for (int t = 0; t < f; ++t)
        *(ushort4*)(attnb + ((size_t)(b * kT + t)) * kC + c) = u;
}

// ---------------------------------------------------------------------------
// Split-s MFMA flash attention (partials). grid (T/64, B*H, kSplit),
// 256 thr = 4 waves; wave wv owns q-rows [x*64+16wv, +16). Split j processes
// s-chunks c ≡ j (mod 4), c <= x (64 s each) -> near-uniform block work.
// Writes unnormalized O (bf16) + (m, l) per q row; merged by attn_merge.
// ---------------------------------------------------------------------------
__global__ __launch_bounds__(256) void attn_partial(const unsigned short* __restrict__ qkv,
                                                    const unsigned short* __restrict__ vt,
                                                    const int* __restrict__ pad,
                                                    unsigned short* __restrict__ Opart,
                                                    float* __restrict__ Mpart,
                                                    float* __restrict__ Lpart) {
    __shared__ __align__(16) unsigned short Ps[4][2][16][40];  // per-wave P, s-halves
    const int tid = threadIdx.x;
    const int x = blockIdx.x, bh = blockIdx.y, j = blockIdx.z;
    const int b = bh >> 4, h = bh & 15;
    const int wv = tid >> 6, lane = tid & 63;
    const int lm = lane & 15, lk = lane >> 4;

    const int qrow = x * 64 + wv * 16 + lm;   // this lane's q column
    const size_t qoff = ((size_t)(b * kT + qrow)) * 3072 + h * 64 + lk * 8;
    short8 bq0 = *(const short8*)(qkv + qoff);
    short8 bq1 = *(const short8*)(qkv + qoff + 32);

    f32x4 o[4];
    #pragma unroll
    for (int dt = 0; dt < 4; dt++) o[dt] = (f32x4){0.f, 0.f, 0.f, 0.f};
    float m_i = -__builtin_inff(), l_i = 0.f;

    for (int c = j; c <= x; c += kSplit) {
        const int s0 = c * 64;
        // --- scores S^T(64s x 16q) = K . Q^T, 4 groups of 16 s ---
        float xs[16];
        #pragma unroll
        for (int g = 0; g < 4; g++) {
            const size_t ko = ((size_t)(b * kT + s0 + g * 16 + lm)) * 3072 + 1024 + h * 64 + lk * 8;
            short8 ka0 = *(const short8*)(qkv + ko);
            short8 ka1 = *(const short8*)(qkv + ko + 32);
            f32x4 sc = (f32x4){0.f, 0.f, 0.f, 0.f};
            sc = __builtin_amdgcn_mfma_f32_16x16x32_bf16(ka0, bq0, sc, 0, 0, 0);
            sc = __builtin_amdgcn_mfma_f32_16x16x32_bf16(ka1, bq1, sc, 0, 0, 0);
            int sbase = s0 + g * 16 + lk * 4;
            int4 pv = *(const int4*)(pad + b * kT + sbase);
            int pa[4] = {pv.x, pv.y, pv.z, pv.w};
            #pragma unroll
            for (int r = 0; r < 4; r++) {
                float v = sc[r] * 0.03125f;           // C^-0.5
                if (sbase + r > qrow) v = -__builtin_inff();
                if (pa[r]) v = -1e9f;                 // pad override last (reference order)
                xs[g * 4 + r] = v;
            }
        }
        // --- online softmax (col q = lm; reduce across lk via xor16/32) ---
        float mt = xs[0];
        #pragma unroll
        for (int i = 1; i < 16; i++) mt = fmaxf(mt, xs[i]);
        mt = fmaxf(mt, __shfl_xor(mt, 16));
        mt = fmaxf(mt, __shfl_xor(mt, 32));
        float mn = fmaxf(m_i, mt);
        float alpha = __expf(m_i - mn);
        float p[16], rs = 0.f;
        #pragma unroll
        for (int i = 0; i < 16; i++) { p[i] = __expf(xs[i] - mn); rs += p[i]; }
        rs += __shfl_xor(rs, 16);
        rs += __shfl_xor(rs, 32);
        l_i = l_i * alpha + rs;
        m_i = mn;
        // --- P -> per-wave LDS [q][s], two 32-s halves ---
        #pragma unroll
        for (int g = 0; g < 4; g++) {
            ushort4 u;
            u.x = f2bf(p[g * 4 + 0]); u.y = f2bf(p[g * 4 + 1]);
            u.z = f2bf(p[g * 4 + 2]); u.w = f2bf(p[g * 4 + 3]);
            *(ushort4*)&Ps[wv][g >> 1][lm][(g & 1) * 16 + lk * 4] = u;
        }
        // --- rescale acc (o rows q' = lk*4+r; alpha uniform across lk) ---
        float ar0 = __shfl(alpha, lk * 4 + 0);
        float ar1 = __shfl(alpha, lk * 4 + 1);
        float ar2 = __shfl(alpha, lk * 4 + 2);
        float ar3 = __shfl(alpha, lk * 4 + 3);
        #pragma unroll
        for (int dt = 0; dt < 4; dt++) {
            o[dt][0] *= ar0; o[dt][1] *= ar1; o[dt][2] *= ar2; o[dt][3] *= ar3;
        }
        // --- O += P V : A = P halves from LDS, B = V^T from global ---
        short8 ap0 = *(const short8*)&Ps[wv][0][lm][lk * 8];
        short8 ap1 = *(const short8*)&Ps[wv][1][lm][lk * 8];
        #pragma unroll
        for (int dt = 0; dt < 4; dt++) {
            const size_t vo = ((size_t)(bh * 64 + dt * 16 + lm)) * kT + s0 + lk * 8;
            short8 bv0 = *(const short8*)(vt + vo);
            short8 bv1 = *(const short8*)(vt + vo + 32);
            o[dt] = __builtin_amdgcn_mfma_f32_16x16x32_bf16(ap0, bv0, o[dt], 0, 0, 0);
            o[dt] = __builtin_amdgcn_mfma_f32_16x16x32_bf16(ap1, bv1, o[dt], 0, 0, 0);
        }
    }
    // --- write partials ---
    const size_t base = ((size_t)(bh * kSplit + j)) * kT;
    if (lk == 0) {
        Mpart[base + qrow] = m_i;
        Lpart[base + qrow] = l_i;
    }
    #pragma unroll
    for (int dt = 0; dt < 4; dt++)
        #pragma unroll
        for (int r = 0; r < 4; r++) {
            int q = x * 64 + wv * 16 + lk * 4 + r;
            Opart[(base + q) * kD + dt * 16 + lm] = f2bf(o[dt][r]);
        }
}

// ---------------------------------------------------------------------------
// Merge split partials -> attnb (B,T,C) bf16. grid (T/64, B*H), 256 thr.
// ---------------------------------------------------------------------------
__global__ __launch_bounds__(256) void attn_merge(const unsigned short* __restrict__ Opart,
                                                  const float* __restrict__ Mpart,
                                                  const float* __restrict__ Lpart,
                                                  unsigned short* __restrict__ attnb) {
    const int xq = blockIdx.x, bh = blockIdx.y;
    const int b = bh >> 4, h = bh & 15;
    const int tid = threadIdx.x;
    const int qo = tid >> 4, d4 = (tid & 15) * 4;
    #pragma unroll
    for (int pass = 0; pass < 4; pass++) {
        int q = xq * 64 + pass * 16 + qo;
        float m[kSplit], l[kSplit];
        float mstar = -__builtin_inff();
        #pragma unroll
        for (int jj = 0; jj < kSplit; jj++) {
            size_t base = ((size_t)(bh * kSplit + jj)) * kT + q;
            m[jj] = Mpart[base];
            l[jj] = Lpart[base];
            if (l[jj] > 0.f) mstar = fmaxf(mstar, m[jj]);
        }
        float acc0 = 0.f, acc1 = 0.f, acc2 = 0.f, acc3 = 0.f, L = 0.f;
        #pragma unroll
        for (int jj = 0; jj < kSplit; jj++) {
            if (l[jj] > 0.f) {
                float wgt = __expf(m[jj] - mstar);
                L += wgt * l[jj];
                ushort4 ov = *(const ushort4*)&Opart[(((size_t)(bh * kSplit + jj)) * kT + q) * kD + d4];
                acc0 += wgt * bf2f(ov.x);
                acc1 += wgt * bf2f(ov.y);
                acc2 += wgt * bf2f(ov.z);
                acc3 += wgt * bf2f(ov.w);
            }
        }
        float inv = 1.0f / L;
        ushort4 r;
        r.x = f2bf(acc0 * inv); r.y = f2bf(acc1 * inv);
        r.z = f2bf(acc2 * inv); r.w = f2bf(acc3 * inv);
        *(ushort4*)&attnb[((size_t)(b * kT + q)) * kC + h * 64 + d4] = r;
    }
}

// ---------------------------------------------------------------------------
// bf16 MFMA GEMM: C(MxN) = A(MxK) . Bt(NxK)^T, fp32 acc. Tile TM x TN, BK=32,
// 256 threads (4 waves, 2x2). Software-pipelined: prefetch next k-chunk into
// regs between barrier and MFMAs so global latency overlaps compute.
// ---------------------------------------------------------------------------
template<int TM, int TN>
__global__ __launch_bounds__(256) void gemm_bt(const unsigned short* __restrict__ A,
                                               const unsigned short* __restrict__ Bt,
                                               const float* __restrict__ bias,
                                               float* __restrict__ Cf,
                                               unsigned short* __restrict__ Cb,
                                               int N, int K, int relu) {
    constexpr int AI = TM / 32, BJ = TN / 32;
    constexpr int AR = TM / 64, BR = TN / 64;
    __shared__ __align__(16) unsigned short As[TM * 32];
    __shared__ __align__(16) unsigned short Bs[TN * 32];
    const int tid = threadIdx.x;
    const int wv = tid >> 6, lane = tid & 63;
    const int lm = lane & 15, lk = lane >> 4;
    const int srow = tid >> 2, sk8 = (tid & 3) * 8;   // staging: row 0..63, k-chunk
    const int bm = blockIdx.y * TM, bn = blockIdx.x * TN;
    const int wm = (wv >> 1) * (TM / 2), wn = (wv & 1) * (TN / 2);
    f32x4 acc[AI][BJ];
    #pragma unroll
    for (int i = 0; i < AI; i++)
        #pragma unroll
        for (int j = 0; j < BJ; j++) acc[i][j] = (f32x4){0.f, 0.f, 0.f, 0.f};

    short8 rA[AR], rB[BR];
    #pragma unroll
    for (int i = 0; i < AR; i++)
        rA[i] = *(const short8*)(A + (size_t)(bm + srow + i * 64) * K + sk8);
    #pragma unroll
    for (int i = 0; i < BR; i++)
        rB[i] = *(const short8*)(Bt + (size_t)(bn + srow + i * 64) * K + sk8);

    for (int k0 = 0; k0 < K; k0 += 32) {
        #pragma unroll
        for (int i = 0; i < AR; i++)
            *(short8*)&As[(srow + i * 64) * 32 + sk8] = rA[i];
        #pragma unroll
        for (int i = 0; i < BR; i++)
            *(short8*)&Bs[(srow + i * 64) * 32 + sk8] = rB[i];
        __syncthreads();
        if (k0 + 32 < K) {
            #pragma unroll
            for (int i = 0; i < AR; i++)
                rA[i] = *(const short8*)(A + (size_t)(bm + srow + i * 64) * K + k0 + 32 + sk8);
            #pragma unroll
            for (int i = 0; i < BR; i++)
                rB[i] = *(const short8*)(Bt + (size_t)(bn + srow + i * 64) * K + k0 + 32 + sk8);
        }
        short8 a[AI], bfr[BJ];
        #pragma unroll
        for (int i = 0; i < AI; i++)
            a[i] = *(const short8*)(As + (wm + i * 16 + lm) * 32 + lk * 8);
        #pragma unroll
        for (int j = 0; j < BJ; j++)
            bfr[j] = *(const short8*)(Bs + (wn + j * 16 + lm) * 32 + lk * 8);
        #pragma unroll
        for (int i = 0; i < AI; i++)
            #pragma unroll
            for (int j = 0; j < BJ; j++)
                acc[i][j] = __builtin_amdgcn_mfma_f32_16x16x32_bf16(a[i], bfr[j], acc[i][j], 0, 0, 0);
        __syncthreads();
    }
    #pragma unroll
    for (int j = 0; j < BJ; j++) {
        int col = bn + wn + j * 16 + lm;
        float bj = bias ? bias[col] : 0.f;
        #pragma unroll
        for (int i = 0; i < AI; i++) {
            #pragma unroll
            for (int r = 0; r < 4; r++) {
                int row = bm + wm + i * 16 + lk * 4 + r;
                float v = acc[i][j][r] + bj;
                if (relu) v = fmaxf(v, 0.f);
                if (Cf) Cf[(size_t)row * N + col] = v;
                else    Cb[(size_t)row * N + col] = f2bf(v);
            }
        }
    }
}

// ---------------------------------------------------------------------------
extern "C" void kernel_launch(void* const* d_in, const int* in_sizes, int n_in,
                              void* d_out, int out_size, void* d_ws, size_t ws_size,
                              hipStream_t stream) {
    (void)in_sizes; (void)n_in; (void)out_size; (void)ws_size;
    const float* x    = (const float*)d_in[0];
    const int*   pad  = (const int*)d_in[1];
    const float* Wq   = (const float*)d_in[2];
    const float* Wk   = (const float*)d_in[3];
    const float* Wv   = (const float*)d_in[4];
    const float* Wo   = (const float*)d_in[5];
    const float* bo   = (const float*)d_in[6];
    const float* ln1g = (const float*)d_in[7];
    const float* ln1b = (const float*)d_in[8];
    const float* ln2g = (const float*)d_in[9];
    const float* ln2b = (const float*)d_in[10];
    const float* W1   = (const float*)d_in[11];
    const float* b1   = (const float*)d_in[12];
    const float* W2   = (const float*)d_in[13];
    const float* b2   = (const float*)d_in[14];
    float* out = (float*)d_out;
    char* w = (char*)d_ws;

    // Workspace map (93 MB total; ws >= 96 MB proven in round 1):
    //  [0,24)  qkv bf16        -> dead after attn_partial; [0,16) reused as proj fp32
    //  [16,24) h2 bf16 (ln2 out; written after proj)
    //  [24,32) vt bf16
    //  [32,40) attnb bf16
    //  [40,48) w1t  [48,56) w2t  [56,58) wot
    //  [58,59) meanv/npad/fu
    //  [59,91) phase-multiplexed: {h [59,67) + wqkvt [67,73)} -> Opart (32MB) -> ffn1 (32MB)
    //  [91,92) Mpart  [92,93) Lpart
    constexpr size_t MB = 1024 * 1024;
    unsigned short* qkv   = (unsigned short*)(w + 0);
    float*          proj  = (float*)(w + 0);
    unsigned short* h2    = (unsigned short*)(w + 16 * MB);
    unsigned short* vt    = (unsigned short*)(w + 24 * MB);
    unsigned short* attnb = (unsigned short*)(w + 32 * MB);
    unsigned short* w1t   = (unsigned short*)(w + 40 * MB);
    unsigned short* w2t   = (unsigned short*)(w + 48 * MB);
    unsigned short* wot   = (unsigned short*)(w + 56 * MB);
    float*          meanv = (float*)(w + 58 * MB);
    int*            npad  = (int*)(w + 58 * MB + 65536);
    int*            fu    = (int*)(w + 58 * MB + 65536 + 64);
    unsigned short* h     = (unsigned short*)(w + 59 * MB);
    unsigned short* wqkvt = (unsigned short*)(w + 67 * MB);
    unsigned short* Opart = (unsigned short*)(w + 59 * MB);  // 64bh*4sp*1024q*64d bf16 = 32 MB
    unsigned short* ffn1  = (unsigned short*)(w + 59 * MB);  // 32 MB, after Opart dead
    float*          Mpart = (float*)(w + 91 * MB);
    float*          Lpart = (float*)(w + 92 * MB);

    // weight conversions (fp32 -> bf16, transposed to N x K)
    transpose_w_kernel<<<dim3(16, 1, 16), 256, 0, stream>>>(Wq, wqkvt,               kC, kD);
    transpose_w_kernel<<<dim3(16, 1, 16), 256, 0, stream>>>(Wk, wqkvt + 1024 * 1024, kC, kD);
    transpose_w_kernel<<<dim3(16, 1, 16), 256, 0, stream>>>(Wv, wqkvt + 2048 * 1024, kC, kD);
    transpose_w_kernel<<<dim3(16, 16, 1), 256, 0, stream>>>(Wo, wot, kC, kC);
    transpose_w_kernel<<<dim3(16, 64, 1), 256, 0, stream>>>(W1, w1t, kC, kF);
    transpose_w_kernel<<<dim3(64, 16, 1), 256, 0, stream>>>(W2, w2t, kF, kC);

    ln_bf16_kernel<<<kBT, 256, 0, stream>>>(x, ln1g, ln1b, h);
    gemm_bt<128, 128><<<dim3(24, 32), 256, 0, stream>>>(h, wqkvt, nullptr, nullptr, qkv,
                                                        3072, kC, 0);
    transpose_v_kernel<<<dim3(16, 64), 256, 0, stream>>>(qkv, vt);
    padscan_kernel<<<kB, 256, 0, stream>>>(pad, npad, fu);
    meanv_kernel<<<kB * kH, 256, 0, stream>>>(vt, pad, npad, meanv);
    attn_partial<<<dim3(16, 64, kSplit), 256, 0, stream>>>(qkv, vt, pad, Opart, Mpart, Lpart);
    attn_merge<<<dim3(16, 64), 256, 0, stream>>>(Opart, Mpart, Lpart, attnb);
    fixup_kernel<<<kB, 256, 0, stream>>>(attnb, meanv, fu);
    gemm_bt<128, 64><<<dim3(16, 32), 256, 0, stream>>>(attnb, wot, bo, proj, nullptr,
                                                       kC, kC, 0);
    ln_bf16_kernel<<<kBT, 256, 0, stream>>>(proj, ln2g, ln2b, h2);
    gemm_bt<128, 128><<<dim3(32, 32), 256, 0, stream>>>(h2, w1t, b1, nullptr, ffn1,
                                                        kF, kC, 1);
    gemm_bt<128, 64><<<dim3(16, 32), 256, 0, stream>>>(ffn1, w2t, b2, out, nullptr,
                                                       kC, kF, 0);
}

// Round 6
// 414.216 us; speedup vs baseline: 4.2386x; 1.2353x over previous
//
#include <hip/hip_runtime.h>
#include <hip/hip_bf16.h>
#include <math.h>

// Problem constants
constexpr int kB = 4;
constexpr int kT = 1024;
constexpr int kC = 1024;
constexpr int kH = 16;
constexpr int kD = 64;
constexpr int kF = 4096;
constexpr int kBT = kB * kT;
constexpr int kSplit = 2;   // attention s-splits

typedef __attribute__((ext_vector_type(8))) short short8;   // bf16x8 MFMA frag (4 VGPRs)
typedef __attribute__((ext_vector_type(4))) float f32x4;    // MFMA acc frag

__device__ __forceinline__ unsigned short f2bf(float f) {
    __hip_bfloat16 h = __float2bfloat16(f);
    return __builtin_bit_cast(unsigned short, h);
}
__device__ __forceinline__ float bf2f(unsigned short u) {
    return __bfloat162float(__builtin_bit_cast(__hip_bfloat16, u));
}

// NOTE: __builtin_amdgcn_global_load_lds is BANNED in this harness — it
// deterministically killed the MI355X container (rounds 2-3 bisect).

// ---------------------------------------------------------------------------
// LayerNorm -> bf16 out. One block per row (C=1024), 256 threads.
// ---------------------------------------------------------------------------
__global__ __launch_bounds__(256) void ln_bf16_kernel(const float* __restrict__ x,
                                                      const float* __restrict__ g,
                                                      const float* __restrict__ bta,
                                                      unsigned short* __restrict__ out) {
    int row = blockIdx.x;
    int t = threadIdx.x;
    float4 xv = ((const float4*)(x + (size_t)row * kC))[t];
    float s  = xv.x + xv.y + xv.z + xv.w;
    float sq = xv.x * xv.x + xv.y * xv.y + xv.z * xv.z + xv.w * xv.w;
    #pragma unroll
    for (int off = 32; off; off >>= 1) {
        s  += __shfl_xor(s, off);
        sq += __shfl_xor(sq, off);
    }
    __shared__ float sb[8];
    int wid = t >> 6, lane = t & 63;
    if (lane == 0) { sb[wid] = s; sb[4 + wid] = sq; }
    __syncthreads();
    s  = sb[0] + sb[1] + sb[2] + sb[3];
    sq = sb[4] + sb[5] + sb[6] + sb[7];
    float mean = s * (1.0f / kC);
    float var  = sq * (1.0f / kC) - mean * mean;
    float rs = rsqrtf(var + 1e-5f);
    float4 gv = ((const float4*)g)[t];
    float4 bv = ((const float4*)bta)[t];
    ushort4 o;
    o.x = f2bf((xv.x - mean) * rs * gv.x + bv.x);
    o.y = f2bf((xv.y - mean) * rs * gv.y + bv.y);
    o.z = f2bf((xv.z - mean) * rs * gv.z + bv.z);
    o.w = f2bf((xv.w - mean) * rs * gv.w + bv.w);
    *(ushort4*)(out + (size_t)row * kC + t * 4) = o;
}

// ---------------------------------------------------------------------------
// Transpose fp32 (R x C) -> bf16 (C x R), batched. grid (R/64, C/64, batch).
// ---------------------------------------------------------------------------
__global__ __launch_bounds__(256) void transpose_w_kernel(const float* __restrict__ src,
                                                          unsigned short* __restrict__ dst,
                                                          int R, int C) {
    __shared__ float tile[64][65];
    src += (size_t)blockIdx.z * R * C;
    dst += (size_t)blockIdx.z * R * C;
    int r0 = blockIdx.x * 64, c0 = blockIdx.y * 64;
    int tid = threadIdx.x;
    int tr = tid >> 4, tc4 = (tid & 15) * 4;
    #pragma unroll
    for (int p = 0; p < 4; p++) {
        float4 v = *(const float4*)(src + (size_t)(r0 + tr + p * 16) * C + c0 + tc4);
        tile[tr + p * 16][tc4 + 0] = v.x;
        tile[tr + p * 16][tc4 + 1] = v.y;
        tile[tr + p * 16][tc4 + 2] = v.z;
        tile[tr + p * 16][tc4 + 3] = v.w;
    }
    __syncthreads();
    #pragma unroll
    for (int p = 0; p < 4; p++) {
        int c = tr + p * 16;
        ushort4 o;
        o.x = f2bf(tile[tc4 + 0][c]);
        o.y = f2bf(tile[tc4 + 1][c]);
        o.z = f2bf(tile[tc4 + 2][c]);
        o.w = f2bf(tile[tc4 + 3][c]);
        *(ushort4*)(dst + (size_t)(c0 + c) * R + r0 + tc4) = o;
    }
}

// ---------------------------------------------------------------------------
// Extract V from qkv buffer and transpose to (B,H,D,T) bf16. grid (T/64, B*H).
// ---------------------------------------------------------------------------
__global__ __launch_bounds__(256) void transpose_v_kernel(const unsigned short* __restrict__ qkv,
                                                          unsigned short* __restrict__ vt) {
    __shared__ unsigned short tile[64][68];
    int bh = blockIdx.y, b = bh >> 4, h = bh & 15;
    int t0 = blockIdx.x * 64;
    int tid = threadIdx.x;
    int tr = tid >> 4, tc4 = (tid & 15) * 4;
    #pragma unroll
    for (int p = 0; p < 4; p++) {
        int t = t0 + tr + p * 16;
        ushort4 v = *(const ushort4*)(qkv + ((size_t)(b * kT + t)) * 3072 + 2048 + h * 64 + tc4);
        *(ushort4*)&tile[tr + p * 16][tc4] = v;
    }
    __syncthreads();
    #pragma unroll
    for (int p = 0; p < 4; p++) {
        int d = tr + p * 16;
        ushort4 o;
        o.x = tile[tc4 + 0][d];
        o.y = tile[tc4 + 1][d];
        o.z = tile[tc4 + 2][d];
        o.w = tile[tc4 + 3][d];
        *(ushort4*)(vt + ((size_t)(bh * 64 + d)) * kT + t0 + tc4) = o;
    }
}

// ---------------------------------------------------------------------------
// Pad scan: Npad[b] and first_unpad[b] = min{t : pad==0} (1024 if none).
// ---------------------------------------------------------------------------
__global__ __launch_bounds__(256) void padscan_kernel(const int* __restrict__ pad,
                                                      int* __restrict__ npad,
                                                      int* __restrict__ fu) {
    int b = blockIdx.x, tid = threadIdx.x;
    int cnt = 0, f = kT;
    for (int t = tid; t < kT; t += 256) {
        int p = pad[b * kT + t];
        cnt += p;
        if (!p) f = min(f, t);
    }
    __shared__ int sc[256], sf[256];
    sc[tid] = cnt; sf[tid] = f;
    __syncthreads();
    for (int o = 128; o; o >>= 1) {
        if (tid < o) { sc[tid] += sc[tid + o]; sf[tid] = min(sf[tid], sf[tid + o]); }
        __syncthreads();
    }
    if (tid == 0) { npad[b] = sc[0]; fu[b] = sf[0]; }
}

// ---------------------------------------------------------------------------
// meanv[b][h][d] = mean over padded t of V. grid (B*H), 256 threads.
// ---------------------------------------------------------------------------
__global__ __launch_bounds__(256) void meanv_kernel(const unsigned short* __restrict__ vt,
                                                    const int* __restrict__ pad,
                                                    const int* __restrict__ npad,
                                                    float* __restrict__ meanv) {
    int bh = blockIdx.x, b = bh >> 4;
    int tid = threadIdx.x, d = tid >> 2, seg = tid & 3;
    const unsigned short* row = vt + ((size_t)bh * 64 + d) * kT + seg * 256;
    const int* pr = pad + b * kT + seg * 256;
    float s = 0.f;
    for (int t = 0; t < 256; ++t)
        if (pr[t]) s += bf2f(row[t]);
    __shared__ float red[256];
    red[tid] = s;
    __syncthreads();
    if (seg == 0) {
        float tot = red[tid] + red[tid + 1] + red[tid + 2] + red[tid + 3];
        int np = npad[b];
        meanv[bh * 64 + d] = np > 0 ? tot / (float)np : 0.f;
    }
}

// ---------------------------------------------------------------------------
// Fixup: rows t < first_unpad[b] attend uniformly to ALL padded keys.
// ---------------------------------------------------------------------------
__global__ __launch_bounds__(256) void fixup_kernel(unsigned short* __restrict__ attnb,
                                                    const float* __restrict__ meanv,
                                                    const int* __restrict__ fu) {
    int b = blockIdx.x, tid = threadIdx.x;
    int f = fu[b];
    int c = tid * 4;
    ushort4 u;
    u.x = f2bf(meanv[b * kC + c + 0]);
    u.y = f2bf(meanv[b * kC + c + 1]);
    u.z = f2bf(meanv[b * kC + c + 2]);
    u.w = f2bf(meanv[b * kC + c + 3]);
    for (int t = 0; t < f; ++t)
        *(ushort4*)(attnb + ((size_t)(b * kT + t)) * kC + c) = u;
}

// ---------------------------------------------------------------------------
// Split-s MFMA flash attention v2: LDS-staged K/V shared by all 4 waves,
// register-prefetch of next chunk during compute (gemm_bt pipeline pattern).
// grid (T/64, B*H, kSplit); wave wv owns q-rows [x*64+16wv, +16); split j
// processes 64-s chunks c ≡ j (mod kSplit), c <= x. Writes unnormalized O
// (bf16) + (m,l); merged by attn_merge. Padded keys give exp(-1e9-m)==0 in
// fp32; all-padded-visible rows handled by fixup_kernel.
// ---------------------------------------------------------------------------
__global__ __launch_bounds__(256) void attn_partial(const unsigned short* __restrict__ qkv,
                                                    const unsigned short* __restrict__ vt,
                                                    const int* __restrict__ pad,
                                                    unsigned short* __restrict__ Opart,
                                                    float* __restrict__ Mpart,
                                                    float* __restrict__ Lpart) {
    __shared__ __align__(16) unsigned short Ks[64][72];   // [s][d], +8 pad
    __shared__ __align__(16) unsigned short Vs[64][72];   // [d][s], +8 pad
    __shared__ __align__(16) unsigned short Ps[4][16][72];// per-wave P [q][s]
    const int tid = threadIdx.x;
    const int x = blockIdx.x, bh = blockIdx.y, j = blockIdx.z;
    const int b = bh >> 4, h = bh & 15;
    const int wv = tid >> 6, lane = tid & 63;
    const int lm = lane & 15, lk = lane >> 4;
    const int srow = tid >> 2, scol = (tid & 3) * 16;   // staging: row, col base

    const int qrow = x * 64 + wv * 16 + lm;
    const size_t qoff = ((size_t)(b * kT + qrow)) * 3072 + h * 64 + lk * 8;
    short8 bq0 = *(const short8*)(qkv + qoff);
    short8 bq1 = *(const short8*)(qkv + qoff + 32);

    // staging base pointers (chunk offset added per iteration)
    const unsigned short* kbase = qkv + ((size_t)(b * kT + srow)) * 3072 + 1024 + h * 64 + scol;
    const unsigned short* vbase = vt + ((size_t)(bh * 64 + srow)) * kT + scol;

    f32x4 o[4];
    #pragma unroll
    for (int dt = 0; dt < 4; dt++) o[dt] = (f32x4){0.f, 0.f, 0.f, 0.f};
    float m_i = -__builtin_inff(), l_i = 0.f;

    // prefetch first chunk (s0 = j*64 <= 64: always in-bounds)
    short8 kp0 = *(const short8*)(kbase + (size_t)(j * 64) * 3072);
    short8 kp1 = *(const short8*)(kbase + (size_t)(j * 64) * 3072 + 8);
    short8 vp0 = *(const short8*)(vbase + j * 64);
    short8 vp1 = *(const short8*)(vbase + j * 64 + 8);

    for (int c = j; c <= x; c += kSplit) {
        const int s0 = c * 64;
        // --- commit staged regs to LDS ---
        *(short8*)&Ks[srow][scol] = kp0;
        *(short8*)&Ks[srow][scol + 8] = kp1;
        *(short8*)&Vs[srow][scol] = vp0;
        *(short8*)&Vs[srow][scol + 8] = vp1;
        __syncthreads();
        // --- prefetch next chunk (overlaps compute) ---
        if (c + kSplit <= x) {
            const int sn = (c + kSplit) * 64;
            kp0 = *(const short8*)(kbase + (size_t)sn * 3072);
            kp1 = *(const short8*)(kbase + (size_t)sn * 3072 + 8);
            vp0 = *(const short8*)(vbase + sn);
            vp1 = *(const short8*)(vbase + sn + 8);
        }
        // --- scores S^T(64s x 16q) = K . Q^T, 4 groups of 16 s, from LDS ---
        float xs[16];
        #pragma unroll
        for (int g = 0; g < 4; g++) {
            short8 ka0 = *(const short8*)&Ks[g * 16 + lm][lk * 8];
            short8 ka1 = *(const short8*)&Ks[g * 16 + lm][32 + lk * 8];
            f32x4 sc = (f32x4){0.f, 0.f, 0.f, 0.f};
            sc = __builtin_amdgcn_mfma_f32_16x16x32_bf16(ka0, bq0, sc, 0, 0, 0);
            sc = __builtin_amdgcn_mfma_f32_16x16x32_bf16(ka1, bq1, sc, 0, 0, 0);
            int sbase = s0 + g * 16 + lk * 4;
            int4 pv = *(const int4*)(pad + b * kT + sbase);
            int pa[4] = {pv.x, pv.y, pv.z, pv.w};
            #pragma unroll
            for (int r = 0; r < 4; r++) {
                float v = sc[r] * 0.03125f;           // C^-0.5
                if (sbase + r > qrow) v = -__builtin_inff();
                if (pa[r]) v = -1e9f;                 // pad override last (reference order)
                xs[g * 4 + r] = v;
            }
        }
        // --- online softmax (col q = lm; reduce across lk via xor16/32) ---
        float mt = xs[0];
        #pragma unroll
        for (int i = 1; i < 16; i++) mt = fmaxf(mt, xs[i]);
        mt = fmaxf(mt, __shfl_xor(mt, 16));
        mt = fmaxf(mt, __shfl_xor(mt, 32));
        float mn = fmaxf(m_i, mt);
        float alpha = __expf(m_i - mn);
        float p[16], rs = 0.f;
        #pragma unroll
        for (int i = 0; i < 16; i++) { p[i] = __expf(xs[i] - mn); rs += p[i]; }
        rs += __shfl_xor(rs, 16);
        rs += __shfl_xor(rs, 32);
        l_i = l_i * alpha + rs;
        m_i = mn;
        // --- P -> per-wave LDS [q][s] ---
        #pragma unroll
        for (int g = 0; g < 4; g++) {
            ushort4 u;
            u.x = f2bf(p[g * 4 + 0]); u.y = f2bf(p[g * 4 + 1]);
            u.z = f2bf(p[g * 4 + 2]); u.w = f2bf(p[g * 4 + 3]);
            *(ushort4*)&Ps[wv][lm][g * 16 + lk * 4] = u;
        }
        // --- rescale acc (o rows q' = lk*4+r; alpha uniform across lk) ---
        float ar0 = __shfl(alpha, lk * 4 + 0);
        float ar1 = __shfl(alpha, lk * 4 + 1);
        float ar2 = __shfl(alpha, lk * 4 + 2);
        float ar3 = __shfl(alpha, lk * 4 + 3);
        #pragma unroll
        for (int dt = 0; dt < 4; dt++) {
            o[dt][0] *= ar0; o[dt][1] *= ar1; o[dt][2] *= ar2; o[dt][3] *= ar3;
        }
        // --- O += P V : A = P from LDS, B = V^T from LDS ---
        short8 ap0 = *(const short8*)&Ps[wv][lm][lk * 8];
        short8 ap1 = *(const short8*)&Ps[wv][lm][32 + lk * 8];
        #pragma unroll
        for (int dt = 0; dt < 4; dt++) {
            short8 bv0 = *(const short8*)&Vs[dt * 16 + lm][lk * 8];
            short8 bv1 = *(const short8*)&Vs[dt * 16 + lm][32 + lk * 8];
            o[dt] = __builtin_amdgcn_mfma_f32_16x16x32_bf16(ap0, bv0, o[dt], 0, 0, 0);
            o[dt] = __builtin_amdgcn_mfma_f32_16x16x32_bf16(ap1, bv1, o[dt], 0, 0, 0);
        }
        __syncthreads();
    }
    // --- write partials ---
    const size_t base = ((size_t)(bh * kSplit + j)) * kT;
    if (lk == 0) {
        Mpart[base + qrow] = m_i;
        Lpart[base + qrow] = l_i;
    }
    #pragma unroll
    for (int dt = 0; dt < 4; dt++)
        #pragma unroll
        for (int r = 0; r < 4; r++) {
            int q = x * 64 + wv * 16 + lk * 4 + r;
            Opart[(base + q) * kD + dt * 16 + lm] = f2bf(o[dt][r]);
        }
}

// ---------------------------------------------------------------------------
// Merge split partials -> attnb (B,T,C) bf16. grid (T/64, B*H), 256 thr.
// ---------------------------------------------------------------------------
__global__ __launch_bounds__(256) void attn_merge(const unsigned short* __restrict__ Opart,
                                                  const float* __restrict__ Mpart,
                                                  const float* __restrict__ Lpart,
                                                  unsigned short* __restrict__ attnb) {
    const int xq = blockIdx.x, bh = blockIdx.y;
    const int b = bh >> 4, h = bh & 15;
    const int tid = threadIdx.x;
    const int qo = tid >> 4, d4 = (tid & 15) * 4;
    #pragma unroll
    for (int pass = 0; pass < 4; pass++) {
        int q = xq * 64 + pass * 16 + qo;
        float m[kSplit], l[kSplit];
        float mstar = -__builtin_inff();
        #pragma unroll
        for (int jj = 0; jj < kSplit; jj++) {
            size_t base = ((size_t)(bh * kSplit + jj)) * kT + q;
            m[jj] = Mpart[base];
            l[jj] = Lpart[base];
            if (l[jj] > 0.f) mstar = fmaxf(mstar, m[jj]);
        }
        float acc0 = 0.f, acc1 = 0.f, acc2 = 0.f, acc3 = 0.f, L = 0.f;
        #pragma unroll
        for (int jj = 0; jj < kSplit; jj++) {
            if (l[jj] > 0.f) {
                float wgt = __expf(m[jj] - mstar);
                L += wgt * l[jj];
                ushort4 ov = *(const ushort4*)&Opart[(((size_t)(bh * kSplit + jj)) * kT + q) * kD + d4];
                acc0 += wgt * bf2f(ov.x);
                acc1 += wgt * bf2f(ov.y);
                acc2 += wgt * bf2f(ov.z);
                acc3 += wgt * bf2f(ov.w);
            }
        }
        float inv = 1.0f / L;
        ushort4 r;
        r.x = f2bf(acc0 * inv); r.y = f2bf(acc1 * inv);
        r.z = f2bf(acc2 * inv); r.w = f2bf(acc3 * inv);
        *(ushort4*)&attnb[((size_t)(b * kT + q)) * kC + h * 64 + d4] = r;
    }
}

// ---------------------------------------------------------------------------
// bf16 MFMA GEMM: C(MxN) = A(MxK) . Bt(NxK)^T, fp32 acc. Tile TM x TN, BK=64
// (32 MFMAs/barrier, halved barrier count vs BK=32), 256 threads (4 waves,
// 2x2). LDS rows padded +8 shorts: staging-write conflicts 16-way -> 2-way,
// frag-read conflicts 8-way -> ~2-way. Register-prefetch pipeline.
// ---------------------------------------------------------------------------
template<int TM, int TN>
__global__ __launch_bounds__(256) void gemm_bt(const unsigned short* __restrict__ A,
                                               const unsigned short* __restrict__ Bt,
                                               const float* __restrict__ bias,
                                               float* __restrict__ Cf,
                                               unsigned short* __restrict__ Cb,
                                               int N, int K, int relu) {
    constexpr int AI = TM / 32, BJ = TN / 32;
    constexpr int TPRA = 256 / TM, TPRB = 256 / TN;   // threads per row
    constexpr int ACH = 64 / TPRA / 8, BCH = 64 / TPRB / 8;  // short8 chunks/thread
    __shared__ __align__(16) unsigned short As[TM][72];
    __shared__ __align__(16) unsigned short Bs[TN][72];
    const int tid = threadIdx.x;
    const int wv = tid >> 6, lane = tid & 63;
    const int lm = lane & 15, lk = lane >> 4;
    const int arow = tid / TPRA, acb = (tid % TPRA) * (64 / TPRA);
    const int brow = tid / TPRB, bcb = (tid % TPRB) * (64 / TPRB);
    const int bm = blockIdx.y * TM, bn = blockIdx.x * TN;
    const int wm = (wv >> 1) * (TM / 2), wn = (wv & 1) * (TN / 2);
    f32x4 acc[AI][BJ];
    #pragma unroll
    for (int i = 0; i < AI; i++)
        #pragma unroll
        for (int j = 0; j < BJ; j++) acc[i][j] = (f32x4){0.f, 0.f, 0.f, 0.f};

    const unsigned short* Ap = A + (size_t)(bm + arow) * K + acb;
    const unsigned short* Bp = Bt + (size_t)(bn + brow) * K + bcb;
    short8 rA[ACH], rB[BCH];
    #pragma unroll
    for (int i = 0; i < ACH; i++) rA[i] = *(const short8*)(Ap + i * 8);
    #pragma unroll
    for (int i = 0; i < BCH; i++) rB[i] = *(const short8*)(Bp + i * 8);

    for (int k0 = 0; k0 < K; k0 += 64) {
        #pragma unroll
        for (int i = 0; i < ACH; i++)
            *(short8*)&As[arow][acb + i * 8] = rA[i];
        #pragma unroll
        for (int i = 0; i < BCH; i++)
            *(short8*)&Bs[brow][bcb + i * 8] = rB[i];
        __syncthreads();
        if (k0 + 64 < K) {
            #pragma unroll
            for (int i = 0; i < ACH; i++) rA[i] = *(const short8*)(Ap + k0 + 64 + i * 8);
            #pragma unroll
            for (int i = 0; i < BCH; i++) rB[i] = *(const short8*)(Bp + k0 + 64 + i * 8);
        }
        #pragma unroll
        for (int kk = 0; kk < 2; kk++) {
            short8 a[AI], bfr[BJ];
            #pragma unroll
            for (int i = 0; i < AI; i++)
                a[i] = *(const short8*)&As[wm + i * 16 + lm][kk * 32 + lk * 8];
            #pragma unroll
            for (int j = 0; j < BJ; j++)
                bfr[j] = *(const short8*)&Bs[wn + j * 16 + lm][kk * 32 + lk * 8];
            #pragma unroll
            for (int i = 0; i < AI; i++)
                #pragma unroll
                for (int j = 0; j < BJ; j++)
                    acc[i][j] = __builtin_amdgcn_mfma_f32_16x16x32_bf16(a[i], bfr[j], acc[i][j], 0, 0, 0);
        }
        __syncthreads();
    }
    #pragma unroll
    for (int j = 0; j < BJ; j++) {
        int col = bn + wn + j * 16 + lm;
        float bj = bias ? bias[col] : 0.f;
        #pragma unroll
        for (int i = 0; i < AI; i++) {
            #pragma unroll
            for (int r = 0; r < 4; r++) {
                int row = bm + wm + i * 16 + lk * 4 + r;
                float v = acc[i][j][r] + bj;
                if (relu) v = fmaxf(v, 0.f);
                if (Cf) Cf[(size_t)row * N + col] = v;
                else    Cb[(size_t)row * N + col] = f2bf(v);
            }
        }
    }
}

// ---------------------------------------------------------------------------
extern "C" void kernel_launch(void* const* d_in, const int* in_sizes, int n_in,
                              void* d_out, int out_size, void* d_ws, size_t ws_size,
                              hipStream_t stream) {
    (void)in_sizes; (void)n_in; (void)out_size; (void)ws_size;
    const float* x    = (const float*)d_in[0];
    const int*   pad  = (const int*)d_in[1];
    const float* Wq   = (const float*)d_in[2];
    const float* Wk   = (const float*)d_in[3];
    const float* Wv   = (const float*)d_in[4];
    const float* Wo   = (const float*)d_in[5];
    const float* bo   = (const float*)d_in[6];
    const float* ln1g = (const float*)d_in[7];
    const float* ln1b = (const float*)d_in[8];
    const float* ln2g = (const float*)d_in[9];
    const float* ln2b = (const float*)d_in[10];
    const float* W1   = (const float*)d_in[11];
    const float* b1   = (const float*)d_in[12];
    const float* W2   = (const float*)d_in[13];
    const float* b2   = (const float*)d_in[14];
    float* out = (float*)d_out;
    char* w = (char*)d_ws;

    // Workspace map (92 MB; ws >= 96 MB proven in round 1):
    //  [0,24)  qkv bf16 -> dead after attn_partial; [0,16) reused as proj fp32
    //  [16,24) h2   [24,32) vt   [32,40) attnb
    //  [40,48) w1t  [48,56) w2t  [56,58) wot
    //  [58,59) meanv/npad/fu
    //  [59,91) phase-multiplexed: {h [59,67) + wqkvt [67,73)} -> Opart (16MB) -> ffn1 (32MB)
    //  [91,91.5) Mpart  [91.5,92) Lpart
    constexpr size_t MB = 1024 * 1024;
    unsigned short* qkv   = (unsigned short*)(w + 0);
    float*          proj  = (float*)(w + 0);
    unsigned short* h2    = (unsigned short*)(w + 16 * MB);
    unsigned short* vt    = (unsigned short*)(w + 24 * MB);
    unsigned short* attnb = (unsigned short*)(w + 32 * MB);
    unsigned short* w1t   = (unsigned short*)(w + 40 * MB);
    unsigned short* w2t   = (unsigned short*)(w + 48 * MB);
    unsigned short* wot   = (unsigned short*)(w + 56 * MB);
    float*          meanv = (float*)(w + 58 * MB);
    int*            npad  = (int*)(w + 58 * MB + 65536);
    int*            fu    = (int*)(w + 58 * MB + 65536 + 64);
    unsigned short* h     = (unsigned short*)(w + 59 * MB);
    unsigned short* wqkvt = (unsigned short*)(w + 67 * MB);
    unsigned short* Opart = (unsigned short*)(w + 59 * MB);  // 64bh*2sp*1024q*64d bf16 = 16 MB
    unsigned short* ffn1  = (unsigned short*)(w + 59 * MB);  // 32 MB, after Opart dead
    float*          Mpart = (float*)(w + 91 * MB);
    float*          Lpart = (float*)(w + 91 * MB + 512 * 1024);

    // weight conversions (fp32 -> bf16, transposed to N x K)
    transpose_w_kernel<<<dim3(16, 1, 16), 256, 0, stream>>>(Wq, wqkvt,               kC, kD);
    transpose_w_kernel<<<dim3(16, 1, 16), 256, 0, stream>>>(Wk, wqkvt + 1024 * 1024, kC, kD);
    transpose_w_kernel<<<dim3(16, 1, 16), 256, 0, stream>>>(Wv, wqkvt + 2048 * 1024, kC, kD);
    transpose_w_kernel<<<dim3(16, 16, 1), 256, 0, stream>>>(Wo, wot, kC, kC);
    transpose_w_kernel<<<dim3(16, 64, 1), 256, 0, stream>>>(W1, w1t, kC, kF);
    transpose_w_kernel<<<dim3(64, 16, 1), 256, 0, stream>>>(W2, w2t, kF, kC);

    ln_bf16_kernel<<<kBT, 256, 0, stream>>>(x, ln1g, ln1b, h);
    gemm_bt<128, 128><<<dim3(24, 32), 256, 0, stream>>>(h, wqkvt, nullptr, nullptr, qkv,
                                                        3072, kC, 0);
    transpose_v_kernel<<<dim3(16, 64), 256, 0, stream>>>(qkv, vt);
    padscan_kernel<<<kB, 256, 0, stream>>>(pad, npad, fu);
    meanv_kernel<<<kB * kH, 256, 0, stream>>>(vt, pad, npad, meanv);
    attn_partial<<<dim3(16, 64, kSplit), 256, 0, stream>>>(qkv, vt, pad, Opart, Mpart, Lpart);
    attn_merge<<<dim3(16, 64), 256, 0, stream>>>(Opart, Mpart, Lpart, attnb);
    fixup_kernel<<<kB, 256, 0, stream>>>(attnb, meanv, fu);
    gemm_bt<128, 64><<<dim3(16, 32), 256, 0, stream>>>(attnb, wot, bo, proj, nullptr,
                                                       kC, kC, 0);
    ln_bf16_kernel<<<kBT, 256, 0, stream>>>(proj, ln2g, ln2b, h2);
    gemm_bt<128, 128><<<dim3(32, 32), 256, 0, stream>>>(h2, w1t, b1, nullptr, ffn1,
                                                        kF, kC, 1);
    gemm_bt<128, 64><<<dim3(16, 32), 256, 0, stream>>>(ffn1, w2t, b2, out, nullptr,
                                                       kC, kF, 0);
}